// Round 7
// baseline (977.692 us; speedup 1.0000x reference)
//
#include <hip/hip_runtime.h>
#include <math.h>

#define IN_DIM_C 128
#define OUT_DIM_C 64
#define T_STEPS 8
#define KC_MAX 512          // max coarse buckets (N/256 = 391 actual)
#define PTILE 2048          // edges per k_part block

__device__ __forceinline__ float4 f4zero() { return make_float4(0.f, 0.f, 0.f, 0.f); }

__device__ __forceinline__ void fma4(float4& a, float xv, const float4 w) {
    a.x = fmaf(xv, w.x, a.x); a.y = fmaf(xv, w.y, a.y);
    a.z = fmaf(xv, w.z, a.z); a.w = fmaf(xv, w.w, a.w);
}

// ---------------- coarse histogram: per-block LDS hist -> global atomics -----------------
// 1563 blocks x 4 edges/thread (more waves/CU than the old 391-block shape)
__global__ __launch_bounds__(256) void k_hist(const int* __restrict__ dst,
                                              int* __restrict__ chist, int E) {
    __shared__ int hh[KC_MAX];
    const int tid = threadIdx.x;
    for (int i = tid; i < KC_MAX; i += 256) hh[i] = 0;
    __syncthreads();
    long base = (long)blockIdx.x * 1024;
    #pragma unroll
    for (int j = 0; j < 4; ++j) {
        long e = base + j * 256 + tid;
        if (e < E) atomicAdd(&hh[dst[e] >> 8], 1);
    }
    __syncthreads();
    for (int i = tid; i < KC_MAX; i += 256)
        if (hh[i]) atomicAdd(&chist[i], hh[i]);
}

// ---------------- tiny scan: exclusive prefix over kc bucket counts -> gcursor -----------
__global__ __launch_bounds__(64) void k_scanK(const int* __restrict__ chist,
                                              int* __restrict__ gcursor,
                                              int* __restrict__ offsets,
                                              int kc, int n, int E) {
    int lane = threadIdx.x;
    int carry = 0;
    for (int c = 0; c * 64 < kc; ++c) {
        int idx = c * 64 + lane;
        int v = (idx < kc) ? chist[idx] : 0;
        int x = v;
        #pragma unroll
        for (int off = 1; off < 64; off <<= 1) {
            int t = __shfl_up(x, off, 64);
            if (lane >= off) x += t;
        }
        if (idx < kc) gcursor[idx] = carry + x - v;
        carry += __shfl(x, 63, 64);
    }
    if (lane == 0) offsets[n] = E;
}

// ---------------- GEMM: h = x @ W, 64-node tile, 4 nodes x 4 dims per thread -------------
__global__ __launch_bounds__(256) void k_gemm(const float* __restrict__ x,
                                              const float* __restrict__ W,
                                              float* __restrict__ h, int n) {
    __shared__ __align__(16) float Ws[IN_DIM_C * OUT_DIM_C];   // 32 KB, [k][d]
    __shared__ __align__(16) float xs[64 * IN_DIM_C];          // 32 KB, [node][k]

    const int tid = threadIdx.x;
    const int node_base = blockIdx.x * 64;
    const float4* x4 = (const float4*)x;
    float4* xs4w = (float4*)xs;

    // stage W: 2048 float4s
    #pragma unroll
    for (int i = 0; i < 8; ++i)
        ((float4*)Ws)[tid + i * 256] = ((const float4*)W)[tid + i * 256];
    // stage 64 x-rows: 2048 float4s (row = idx>>5, c4 = idx&31)
    #pragma unroll
    for (int i = 0; i < 8; ++i) {
        int idx = tid + i * 256;
        int row = idx >> 5, c4 = idx & 31;
        int node = node_base + row;
        xs4w[idx] = (node < n) ? x4[(long)node * 32 + c4] : f4zero();
    }
    __syncthreads();

    const int ng = tid >> 4;     // node group 0..15 -> nodes ng*4..ng*4+3
    const int dg = tid & 15;     // dim group 0..15 -> dims dg*4..dg*4+3
    const float4* Ws4 = (const float4*)Ws;
    const float4* xs4 = (const float4*)xs;

    float4 acc[4] = {f4zero(), f4zero(), f4zero(), f4zero()};
    #pragma unroll
    for (int c = 0; c < 32; ++c) {          // k-chunk of 4
        float4 xv0 = xs4[(ng * 4 + 0) * 32 + c];
        float4 xv1 = xs4[(ng * 4 + 1) * 32 + c];
        float4 xv2 = xs4[(ng * 4 + 2) * 32 + c];
        float4 xv3 = xs4[(ng * 4 + 3) * 32 + c];
        float4 w0 = Ws4[(c * 4 + 0) * 16 + dg];
        float4 w1 = Ws4[(c * 4 + 1) * 16 + dg];
        float4 w2 = Ws4[(c * 4 + 2) * 16 + dg];
        float4 w3 = Ws4[(c * 4 + 3) * 16 + dg];
        fma4(acc[0], xv0.x, w0); fma4(acc[0], xv0.y, w1);
        fma4(acc[0], xv0.z, w2); fma4(acc[0], xv0.w, w3);
        fma4(acc[1], xv1.x, w0); fma4(acc[1], xv1.y, w1);
        fma4(acc[1], xv1.z, w2); fma4(acc[1], xv1.w, w3);
        fma4(acc[2], xv2.x, w0); fma4(acc[2], xv2.y, w1);
        fma4(acc[2], xv2.z, w2); fma4(acc[2], xv2.w, w3);
        fma4(acc[3], xv3.x, w0); fma4(acc[3], xv3.y, w1);
        fma4(acc[3], xv3.z, w2); fma4(acc[3], xv3.w, w3);
    }
    float4* h4 = (float4*)h;
    #pragma unroll
    for (int j = 0; j < 4; ++j) {
        int node = node_base + ng * 4 + j;
        if (node < n) h4[(long)node * 16 + dg] = acc[j];
    }
}

// ---------------- coarse partition: direct scattered stores into per-bucket runs ---------
__global__ __launch_bounds__(512) void k_part(const int* __restrict__ src,
                                              const int* __restrict__ dst,
                                              int* __restrict__ gcursor,
                                              int* __restrict__ part, int E, int kc) {
    __shared__ int hist[KC_MAX];
    __shared__ int offs[KC_MAX];
    __shared__ int cur[KC_MAX];
    __shared__ int gbase[KC_MAX];
    const int tid = threadIdx.x;
    long base = (long)blockIdx.x * PTILE;

    for (int i = tid; i < KC_MAX; i += 512) hist[i] = 0;
    __syncthreads();
    #pragma unroll
    for (int j = 0; j < PTILE / 512; ++j) {
        long e = base + j * 512 + tid;
        if (e < E) atomicAdd(&hist[dst[e] >> 8], 1);
    }
    __syncthreads();
    if (tid < 64) {
        int carry = 0;
        for (int c = 0; c * 64 < kc; ++c) {
            int idx = c * 64 + tid;
            int v = (idx < kc) ? hist[idx] : 0;
            int x = v;
            #pragma unroll
            for (int off = 1; off < 64; off <<= 1) {
                int t = __shfl_up(x, off, 64);
                if (tid >= off) x += t;
            }
            if (idx < kc) { offs[idx] = carry + x - v; cur[idx] = carry + x - v; }
            carry += __shfl(x, 63, 64);
        }
    }
    __syncthreads();
    for (int b = tid; b < kc; b += 512)
        gbase[b] = hist[b] ? atomicAdd(&gcursor[b], hist[b]) : 0;
    __syncthreads();
    #pragma unroll
    for (int j = 0; j < PTILE / 512; ++j) {
        long e = base + j * 512 + tid;
        if (e < E) {
            int d = dst[e];
            int b = d >> 8;
            int r = atomicAdd(&cur[b], 1);
            part[gbase[b] + r - offs[b]] = (src[e] << 8) | (d & 255);
        }
    }
}

// ---------------- fine sort within bucket: counting sort, 1024 threads -------------------
__global__ __launch_bounds__(1024) void k_sort(const int* __restrict__ part,
                                               const int* __restrict__ gcursor,
                                               int* __restrict__ part2,
                                               int* __restrict__ offsets,
                                               float* __restrict__ dinv, int n) {
    __shared__ int cnt[256];
    __shared__ int cur[256];
    __shared__ int wsum[4], woff[4];
    const int tid = threadIdx.x;
    const int bkt = blockIdx.x;
    int start = bkt ? gcursor[bkt - 1] : 0;   // post-partition: gcursor[b] == end(b)
    int end = gcursor[bkt];

    if (tid < 256) cnt[tid] = 0;
    __syncthreads();
    for (int i = start + tid; i < end; i += 1024)
        atomicAdd(&cnt[part[i] & 255], 1);
    __syncthreads();

    int v = (tid < 256) ? cnt[tid] : 0;
    int lane = tid & 63, wv = tid >> 6;
    int x = v;
    #pragma unroll
    for (int off = 1; off < 64; off <<= 1) {
        int t = __shfl_up(x, off, 64);
        if (lane >= off) x += t;
    }
    if (tid < 256 && lane == 63) wsum[wv] = x;
    __syncthreads();
    if (tid == 0) { int c = 0; for (int w = 0; w < 4; ++w) { woff[w] = c; c += wsum[w]; } }
    __syncthreads();
    if (tid < 256) {
        int myloc = woff[wv] + x - v;            // exclusive local offset
        cur[tid] = myloc;
        int node = (bkt << 8) + tid;
        if (node < n) {
            offsets[node] = start + myloc;
            dinv[node] = rsqrtf((float)(v + 1));
        }
    }
    __syncthreads();

    for (int i = start + tid; i < end; i += 1024) {
        int p = part[i];
        int r = atomicAdd(&cur[p & 255], 1);
        part2[start + r] = ((unsigned)p) >> 8;   // src node id
    }
}

// ---------------- fused pull + spiking recurrence: one wave per node, lane = dim ---------
// SAFE ONLY when h/part2/offsets/dinv live outside z_seq (d_ws).
__global__ __launch_bounds__(256) void k_pullspike(const int* __restrict__ offsets,
                                                   const int* __restrict__ part2,
                                                   const float* __restrict__ dinv,
                                                   const float* __restrict__ h,
                                                   const float* __restrict__ b,
                                                   float* __restrict__ o_seq,
                                                   float* __restrict__ z_seq, int n) {
    int node = (blockIdx.x * 256 + threadIdx.x) >> 6;
    int lane = threadIdx.x & 63;
    if (node >= n) return;

    int o0 = offsets[node], o1 = offsets[node + 1];
    float dd = dinv[node];
    float g = fmaf(dd * dd, h[(long)node * OUT_DIM_C + lane], b[lane]);

    // shuffle-distributed gather: per 64 edges, 1 coalesced part2 load + 1 dinv gather
    for (int base = o0; base < o1; base += 64) {
        int m = o1 - base; if (m > 64) m = 64;
        int s_l = 0; float dv_l = 0.f;
        if (base + lane < o1) {
            s_l = part2[base + lane];
            dv_l = dinv[s_l];
        }
        int k = 0;
        for (; k + 8 <= m; k += 8) {
            float hv[8], w[8];
            #pragma unroll
            for (int j = 0; j < 8; ++j) {
                int s = __shfl(s_l, k + j, 64);
                w[j] = __shfl(dv_l, k + j, 64);
                hv[j] = h[(long)s * OUT_DIM_C + lane];
            }
            #pragma unroll
            for (int j = 0; j < 8; ++j) g = fmaf(w[j] * dd, hv[j], g);
        }
        for (; k < m; ++k) {
            int s = __shfl(s_l, k, 64);
            float w = __shfl(dv_l, k, 64);
            g = fmaf(w * dd, h[(long)s * OUT_DIM_C + lane], g);
        }
    }

    const float s0 = (lane == 0) ? -1.0f : 1.0f;
    const float zo = (lane == 0) ? 1.0f : 0.0f;    // origin

    auto step = [&](float z, float& zn, bool& sp) {
        float p = s0 * z * g;
        p += __shfl_xor(p, 1, 64);  p += __shfl_xor(p, 2, 64);
        p += __shfl_xor(p, 4, 64);  p += __shfl_xor(p, 8, 64);
        p += __shfl_xor(p, 16, 64); p += __shfl_xor(p, 32, 64);
        float u = fmaf(p, z, g);
        float q = s0 * u * u;
        q += __shfl_xor(q, 1, 64);  q += __shfl_xor(q, 2, 64);
        q += __shfl_xor(q, 4, 64);  q += __shfl_xor(q, 8, 64);
        q += __shfl_xor(q, 16, 64); q += __shfl_xor(q, 32, 64);
        float un = sqrtf(fmaxf(q, 1e-7f));
        float c = coshf(un);
        float sh = sinhf(un) / un;
        zn = fmaf(c, z, sh * u);
        float z0 = __shfl(zn, 0, 64);
        float v = acoshf(fmaxf(z0, 1.0f + 1e-7f));
        sp = (v >= 1.0f);
    };

    float z1; bool sp0;
    step(zo, z1, sp0);
    float r0 = sp0 ? zo : z1;

    float z = zo;
    bool at0 = true;
    for (int t = 0; t < T_STEPS; ++t) {
        float zn; bool sp;
        if (at0) { sp = sp0; zn = r0; }
        else {
            step(z, zn, sp);
            if (sp) zn = zo;
        }
        z_seq[(long)t * n * OUT_DIM_C + (long)node * OUT_DIM_C + lane] = zn;
        if (lane == 0) o_seq[(long)t * n + node] = sp ? 1.0f : 0.0f;
        z = zn;
        at0 = sp;
    }
}

// ---------------- unfused fallback pair (scratch aliased into z_seq slabs) ---------------
__global__ __launch_bounds__(256) void k_pull(const int* __restrict__ offsets,
                                              const int* __restrict__ part2,
                                              const float* __restrict__ dinv,
                                              const float* __restrict__ h,
                                              const float* __restrict__ b,
                                              float* __restrict__ agg, int n) {
    int node = (blockIdx.x * 256 + threadIdx.x) >> 6;
    int lane = threadIdx.x & 63;
    if (node >= n) return;
    int o0 = offsets[node], o1 = offsets[node + 1];
    float dd = dinv[node];
    float acc = fmaf(dd * dd, h[(long)node * OUT_DIM_C + lane], b[lane]);
    for (int i = o0; i < o1; ++i) {
        int s = part2[i];
        acc = fmaf(dinv[s] * dd, h[(long)s * OUT_DIM_C + lane], acc);
    }
    agg[(long)node * OUT_DIM_C + lane] = acc;
}

__global__ __launch_bounds__(256) void k_spike(const float* agg,
                                               float* o_seq, float* z_seq, int n) {
    int node = (blockIdx.x * 256 + threadIdx.x) >> 6;
    int lane = threadIdx.x & 63;
    if (node >= n) return;
    float g = agg[(long)node * OUT_DIM_C + lane];
    const float s0 = (lane == 0) ? -1.0f : 1.0f;
    const float zo = (lane == 0) ? 1.0f : 0.0f;

    auto step = [&](float z, float& zn, bool& sp) {
        float p = s0 * z * g;
        p += __shfl_xor(p, 1, 64);  p += __shfl_xor(p, 2, 64);
        p += __shfl_xor(p, 4, 64);  p += __shfl_xor(p, 8, 64);
        p += __shfl_xor(p, 16, 64); p += __shfl_xor(p, 32, 64);
        float u = fmaf(p, z, g);
        float q = s0 * u * u;
        q += __shfl_xor(q, 1, 64);  q += __shfl_xor(q, 2, 64);
        q += __shfl_xor(q, 4, 64);  q += __shfl_xor(q, 8, 64);
        q += __shfl_xor(q, 16, 64); q += __shfl_xor(q, 32, 64);
        float un = sqrtf(fmaxf(q, 1e-7f));
        float c = coshf(un);
        float sh = sinhf(un) / un;
        zn = fmaf(c, z, sh * u);
        float z0 = __shfl(zn, 0, 64);
        float v = acoshf(fmaxf(z0, 1.0f + 1e-7f));
        sp = (v >= 1.0f);
    };

    float z1; bool sp0;
    step(zo, z1, sp0);
    float r0 = sp0 ? zo : z1;

    float z = zo;
    bool at0 = true;
    for (int t = 0; t < T_STEPS; ++t) {
        float zn; bool sp;
        if (at0) { sp = sp0; zn = r0; }
        else {
            step(z, zn, sp);
            if (sp) zn = zo;
        }
        z_seq[(long)t * n * OUT_DIM_C + (long)node * OUT_DIM_C + lane] = zn;
        if (lane == 0) o_seq[(long)t * n + node] = sp ? 1.0f : 0.0f;
        z = zn;
        at0 = sp;
    }
}

extern "C" void kernel_launch(void* const* d_in, const int* in_sizes, int n_in,
                              void* d_out, int out_size, void* d_ws, size_t ws_size,
                              hipStream_t stream) {
    const float* x  = (const float*)d_in[0];
    const int*   ei = (const int*)d_in[1];
    const float* W  = (const float*)d_in[2];
    const float* b  = (const float*)d_in[3];
    const int N = in_sizes[0] / IN_DIM_C;   // 100000
    const int E = in_sizes[1] / 2;          // 1600000
    const int KC = (N + 255) >> 8;          // 391 coarse buckets

    float* out   = (float*)d_out;
    float* o_seq = out;                              // [T, N]
    float* z_seq = out + (long)T_STEPS * N;          // [T, N, 64]

    const int* srcp = ei;
    const int* dstp = ei + E;

    const long n_h = (long)N * OUT_DIM_C;
    const long n_meta = 2L * KC_MAX + (N + 1) + N;
    const size_t need = (size_t)(n_h + 2L * E + n_meta) * 4;

    float *h; int *part, *part2, *chist, *gcursor, *offsets; float *dinv;
    bool fused = (ws_size >= need);
    if (fused) {
        h       = (float*)d_ws;
        part    = (int*)(h + n_h);
        part2   = part + E;
        chist   = part2 + E;
    } else {
        h       = z_seq + 1L * n_h;
        part    = (int*)(z_seq + 2L * n_h);
        part2   = (int*)(z_seq + 3L * n_h);
        chist   = (int*)(z_seq + 4L * n_h);
    }
    gcursor = chist + KC_MAX;
    offsets = gcursor + KC_MAX;
    dinv    = (float*)(offsets + N + 1);

    hipMemsetAsync(chist, 0, (size_t)KC_MAX * sizeof(int), stream);
    k_hist<<<(E + 1023) / 1024, 256, 0, stream>>>(dstp, chist, E);
    k_scanK<<<1, 64, 0, stream>>>(chist, gcursor, offsets, KC, N, E);

    k_gemm<<<(N + 63) / 64, 256, 0, stream>>>(x, W, h, N);

    k_part<<<(E + PTILE - 1) / PTILE, 512, 0, stream>>>(srcp, dstp, gcursor, part, E, KC);
    k_sort<<<KC, 1024, 0, stream>>>(part, gcursor, part2, offsets, dinv, N);

    if (fused) {
        k_pullspike<<<(N * 64 + 255) / 256, 256, 0, stream>>>(offsets, part2, dinv, h, b,
                                                              o_seq, z_seq, N);
    } else {
        float* agg = z_seq;   // slab 0
        k_pull<<<(N * 64 + 255) / 256, 256, 0, stream>>>(offsets, part2, dinv, h, b, agg, N);
        k_spike<<<(N * 64 + 255) / 256, 256, 0, stream>>>(agg, o_seq, z_seq, N);
    }
}

// Round 8
// 443.841 us; speedup vs baseline: 2.2028x; 2.2028x over previous
//
#include <hip/hip_runtime.h>
#include <math.h>

#define IN_DIM_C 128
#define OUT_DIM_C 64
#define T_STEPS 8
#define KC_MAX 512          // max coarse buckets (N/256 = 391 actual)
#define PTILE 2048          // edges per k_part block

__device__ __forceinline__ float4 f4zero() { return make_float4(0.f, 0.f, 0.f, 0.f); }

// ---------------- coarse histogram: per-block LDS hist -> global atomics -----------------
__global__ __launch_bounds__(256) void k_hist(const int* __restrict__ dst,
                                              int* __restrict__ chist, int E) {
    __shared__ int hh[KC_MAX];
    const int tid = threadIdx.x;
    for (int i = tid; i < KC_MAX; i += 256) hh[i] = 0;
    __syncthreads();
    long base = (long)blockIdx.x * 1024;
    #pragma unroll
    for (int j = 0; j < 4; ++j) {
        long e = base + j * 256 + tid;
        if (e < E) atomicAdd(&hh[dst[e] >> 8], 1);
    }
    __syncthreads();
    for (int i = tid; i < KC_MAX; i += 256)
        if (hh[i]) atomicAdd(&chist[i], hh[i]);
}

// ---------------- tiny scan: exclusive prefix over kc bucket counts -> gcursor -----------
__global__ __launch_bounds__(64) void k_scanK(const int* __restrict__ chist,
                                              int* __restrict__ gcursor,
                                              int* __restrict__ offsets,
                                              int kc, int n, int E) {
    int lane = threadIdx.x;
    int carry = 0;
    for (int c = 0; c * 64 < kc; ++c) {
        int idx = c * 64 + lane;
        int v = (idx < kc) ? chist[idx] : 0;
        int x = v;
        #pragma unroll
        for (int off = 1; off < 64; off <<= 1) {
            int t = __shfl_up(x, off, 64);
            if (lane >= off) x += t;
        }
        if (idx < kc) gcursor[idx] = carry + x - v;
        carry += __shfl(x, 63, 64);
    }
    if (lane == 0) offsets[n] = E;
}

// ---------------- GEMM: h = x @ W  (round-4 proven: 16 nodes x 16 dim-groups) ------------
// VGPR-lean; xs padded to stride 136 (=17 float4s) -> bank-conflict-free.
__global__ __launch_bounds__(256) void k_gemm(const float* __restrict__ x,
                                              const float* __restrict__ W,
                                              float* __restrict__ h,
                                              int n, int n_groups) {
    __shared__ __align__(16) float Ws[IN_DIM_C * OUT_DIM_C];   // 32 KB, [k][d]
    __shared__ __align__(16) float xs[16 * 136];               // 16 rows, padded stride 136

    for (int i = threadIdx.x; i < IN_DIM_C * OUT_DIM_C / 4; i += 256)
        ((float4*)Ws)[i] = ((const float4*)W)[i];

    const int ln = threadIdx.x >> 4;   // local node 0..15
    const int dg = threadIdx.x & 15;   // dim group 0..15 -> dims 4*dg..4*dg+3
    const float4* Ws4 = (const float4*)Ws;

    for (int g = blockIdx.x; g < n_groups; g += gridDim.x) {
        int node_base = g * 16;
        __syncthreads();
        for (int f = threadIdx.x; f < 512; f += 256) {
            int row = f >> 5, c4 = f & 31;
            int node = node_base + row;
            float4 v = f4zero();
            if (node < n) v = *(const float4*)&x[(long)node * IN_DIM_C + c4 * 4];
            *(float4*)&xs[row * 136 + c4 * 4] = v;
        }
        __syncthreads();

        int node = node_base + ln;
        float4 acc = f4zero();
        #pragma unroll
        for (int k = 0; k < IN_DIM_C; k += 4) {
            float4 xv = *(const float4*)&xs[ln * 136 + k];
            float4 w0 = Ws4[(k + 0) * 16 + dg];
            float4 w1 = Ws4[(k + 1) * 16 + dg];
            float4 w2 = Ws4[(k + 2) * 16 + dg];
            float4 w3 = Ws4[(k + 3) * 16 + dg];
            acc.x = fmaf(xv.x, w0.x, acc.x); acc.y = fmaf(xv.x, w0.y, acc.y);
            acc.z = fmaf(xv.x, w0.z, acc.z); acc.w = fmaf(xv.x, w0.w, acc.w);
            acc.x = fmaf(xv.y, w1.x, acc.x); acc.y = fmaf(xv.y, w1.y, acc.y);
            acc.z = fmaf(xv.y, w1.z, acc.z); acc.w = fmaf(xv.y, w1.w, acc.w);
            acc.x = fmaf(xv.z, w2.x, acc.x); acc.y = fmaf(xv.z, w2.y, acc.y);
            acc.z = fmaf(xv.z, w2.z, acc.z); acc.w = fmaf(xv.z, w2.w, acc.w);
            acc.x = fmaf(xv.w, w3.x, acc.x); acc.y = fmaf(xv.w, w3.y, acc.y);
            acc.z = fmaf(xv.w, w3.z, acc.z); acc.w = fmaf(xv.w, w3.w, acc.w);
        }
        if (node < n)
            *(float4*)&h[(long)node * OUT_DIM_C + dg * 4] = acc;
    }
}

// ---------------- coarse partition: direct scattered stores into per-bucket runs ---------
__global__ __launch_bounds__(512) void k_part(const int* __restrict__ src,
                                              const int* __restrict__ dst,
                                              int* __restrict__ gcursor,
                                              int* __restrict__ part, int E, int kc) {
    __shared__ int hist[KC_MAX];
    __shared__ int offs[KC_MAX];
    __shared__ int cur[KC_MAX];
    __shared__ int gbase[KC_MAX];
    const int tid = threadIdx.x;
    long base = (long)blockIdx.x * PTILE;

    for (int i = tid; i < KC_MAX; i += 512) hist[i] = 0;
    __syncthreads();
    #pragma unroll
    for (int j = 0; j < PTILE / 512; ++j) {
        long e = base + j * 512 + tid;
        if (e < E) atomicAdd(&hist[dst[e] >> 8], 1);
    }
    __syncthreads();
    if (tid < 64) {
        int carry = 0;
        for (int c = 0; c * 64 < kc; ++c) {
            int idx = c * 64 + tid;
            int v = (idx < kc) ? hist[idx] : 0;
            int x = v;
            #pragma unroll
            for (int off = 1; off < 64; off <<= 1) {
                int t = __shfl_up(x, off, 64);
                if (tid >= off) x += t;
            }
            if (idx < kc) { offs[idx] = carry + x - v; cur[idx] = carry + x - v; }
            carry += __shfl(x, 63, 64);
        }
    }
    __syncthreads();
    for (int b = tid; b < kc; b += 512)
        gbase[b] = hist[b] ? atomicAdd(&gcursor[b], hist[b]) : 0;
    __syncthreads();
    #pragma unroll
    for (int j = 0; j < PTILE / 512; ++j) {
        long e = base + j * 512 + tid;
        if (e < E) {
            int d = dst[e];
            int b = d >> 8;
            int r = atomicAdd(&cur[b], 1);
            part[gbase[b] + r - offs[b]] = (src[e] << 8) | (d & 255);
        }
    }
}

// ---------------- fine sort within bucket: counting sort, 1024 threads -------------------
__global__ __launch_bounds__(1024) void k_sort(const int* __restrict__ part,
                                               const int* __restrict__ gcursor,
                                               int* __restrict__ part2,
                                               int* __restrict__ offsets,
                                               float* __restrict__ dinv, int n) {
    __shared__ int cnt[256];
    __shared__ int cur[256];
    __shared__ int wsum[4], woff[4];
    const int tid = threadIdx.x;
    const int bkt = blockIdx.x;
    int start = bkt ? gcursor[bkt - 1] : 0;   // post-partition: gcursor[b] == end(b)
    int end = gcursor[bkt];

    if (tid < 256) cnt[tid] = 0;
    __syncthreads();
    for (int i = start + tid; i < end; i += 1024)
        atomicAdd(&cnt[part[i] & 255], 1);
    __syncthreads();

    int v = (tid < 256) ? cnt[tid] : 0;
    int lane = tid & 63, wv = tid >> 6;
    int x = v;
    #pragma unroll
    for (int off = 1; off < 64; off <<= 1) {
        int t = __shfl_up(x, off, 64);
        if (lane >= off) x += t;
    }
    if (tid < 256 && lane == 63) wsum[wv] = x;
    __syncthreads();
    if (tid == 0) { int c = 0; for (int w = 0; w < 4; ++w) { woff[w] = c; c += wsum[w]; } }
    __syncthreads();
    if (tid < 256) {
        int myloc = woff[wv] + x - v;            // exclusive local offset
        cur[tid] = myloc;
        int node = (bkt << 8) + tid;
        if (node < n) {
            offsets[node] = start + myloc;
            dinv[node] = rsqrtf((float)(v + 1));
        }
    }
    __syncthreads();

    for (int i = start + tid; i < end; i += 1024) {
        int p = part[i];
        int r = atomicAdd(&cur[p & 255], 1);
        part2[start + r] = ((unsigned)p) >> 8;   // src node id
    }
}

// ---------------- fused pull + spiking recurrence: one wave per node, lane = dim ---------
// SAFE ONLY when h/part2/offsets/dinv live outside z_seq (d_ws).
__global__ __launch_bounds__(256) void k_pullspike(const int* __restrict__ offsets,
                                                   const int* __restrict__ part2,
                                                   const float* __restrict__ dinv,
                                                   const float* __restrict__ h,
                                                   const float* __restrict__ b,
                                                   float* __restrict__ o_seq,
                                                   float* __restrict__ z_seq, int n) {
    int node = (blockIdx.x * 256 + threadIdx.x) >> 6;
    int lane = threadIdx.x & 63;
    if (node >= n) return;

    int o0 = offsets[node], o1 = offsets[node + 1];
    float dd = dinv[node];
    float g = fmaf(dd * dd, h[(long)node * OUT_DIM_C + lane], b[lane]);

    // shuffle-distributed gather: per 64 edges, 1 coalesced part2 load + 1 dinv gather
    for (int base = o0; base < o1; base += 64) {
        int m = o1 - base; if (m > 64) m = 64;
        int s_l = 0; float dv_l = 0.f;
        if (base + lane < o1) {
            s_l = part2[base + lane];
            dv_l = dinv[s_l];
        }
        int k = 0;
        for (; k + 8 <= m; k += 8) {
            float hv[8], w[8];
            #pragma unroll
            for (int j = 0; j < 8; ++j) {
                int s = __shfl(s_l, k + j, 64);
                w[j] = __shfl(dv_l, k + j, 64);
                hv[j] = h[(long)s * OUT_DIM_C + lane];
            }
            #pragma unroll
            for (int j = 0; j < 8; ++j) g = fmaf(w[j] * dd, hv[j], g);
        }
        for (; k < m; ++k) {
            int s = __shfl(s_l, k, 64);
            float w = __shfl(dv_l, k, 64);
            g = fmaf(w * dd, h[(long)s * OUT_DIM_C + lane], g);
        }
    }

    const float s0 = (lane == 0) ? -1.0f : 1.0f;
    const float zo = (lane == 0) ? 1.0f : 0.0f;    // origin

    auto step = [&](float z, float& zn, bool& sp) {
        float p = s0 * z * g;
        p += __shfl_xor(p, 1, 64);  p += __shfl_xor(p, 2, 64);
        p += __shfl_xor(p, 4, 64);  p += __shfl_xor(p, 8, 64);
        p += __shfl_xor(p, 16, 64); p += __shfl_xor(p, 32, 64);
        float u = fmaf(p, z, g);
        float q = s0 * u * u;
        q += __shfl_xor(q, 1, 64);  q += __shfl_xor(q, 2, 64);
        q += __shfl_xor(q, 4, 64);  q += __shfl_xor(q, 8, 64);
        q += __shfl_xor(q, 16, 64); q += __shfl_xor(q, 32, 64);
        float un = sqrtf(fmaxf(q, 1e-7f));
        float c = coshf(un);
        float sh = sinhf(un) / un;
        zn = fmaf(c, z, sh * u);
        float z0 = __shfl(zn, 0, 64);
        float v = acoshf(fmaxf(z0, 1.0f + 1e-7f));
        sp = (v >= 1.0f);
    };

    float z1; bool sp0;
    step(zo, z1, sp0);
    float r0 = sp0 ? zo : z1;

    float z = zo;
    bool at0 = true;
    for (int t = 0; t < T_STEPS; ++t) {
        float zn; bool sp;
        if (at0) { sp = sp0; zn = r0; }
        else {
            step(z, zn, sp);
            if (sp) zn = zo;
        }
        z_seq[(long)t * n * OUT_DIM_C + (long)node * OUT_DIM_C + lane] = zn;
        if (lane == 0) o_seq[(long)t * n + node] = sp ? 1.0f : 0.0f;
        z = zn;
        at0 = sp;
    }
}

// ---------------- unfused fallback pair (scratch aliased into z_seq slabs) ---------------
__global__ __launch_bounds__(256) void k_pull(const int* __restrict__ offsets,
                                              const int* __restrict__ part2,
                                              const float* __restrict__ dinv,
                                              const float* __restrict__ h,
                                              const float* __restrict__ b,
                                              float* __restrict__ agg, int n) {
    int node = (blockIdx.x * 256 + threadIdx.x) >> 6;
    int lane = threadIdx.x & 63;
    if (node >= n) return;
    int o0 = offsets[node], o1 = offsets[node + 1];
    float dd = dinv[node];
    float acc = fmaf(dd * dd, h[(long)node * OUT_DIM_C + lane], b[lane]);
    for (int i = o0; i < o1; ++i) {
        int s = part2[i];
        acc = fmaf(dinv[s] * dd, h[(long)s * OUT_DIM_C + lane], acc);
    }
    agg[(long)node * OUT_DIM_C + lane] = acc;
}

__global__ __launch_bounds__(256) void k_spike(const float* agg,
                                               float* o_seq, float* z_seq, int n) {
    int node = (blockIdx.x * 256 + threadIdx.x) >> 6;
    int lane = threadIdx.x & 63;
    if (node >= n) return;
    float g = agg[(long)node * OUT_DIM_C + lane];
    const float s0 = (lane == 0) ? -1.0f : 1.0f;
    const float zo = (lane == 0) ? 1.0f : 0.0f;

    auto step = [&](float z, float& zn, bool& sp) {
        float p = s0 * z * g;
        p += __shfl_xor(p, 1, 64);  p += __shfl_xor(p, 2, 64);
        p += __shfl_xor(p, 4, 64);  p += __shfl_xor(p, 8, 64);
        p += __shfl_xor(p, 16, 64); p += __shfl_xor(p, 32, 64);
        float u = fmaf(p, z, g);
        float q = s0 * u * u;
        q += __shfl_xor(q, 1, 64);  q += __shfl_xor(q, 2, 64);
        q += __shfl_xor(q, 4, 64);  q += __shfl_xor(q, 8, 64);
        q += __shfl_xor(q, 16, 64); q += __shfl_xor(q, 32, 64);
        float un = sqrtf(fmaxf(q, 1e-7f));
        float c = coshf(un);
        float sh = sinhf(un) / un;
        zn = fmaf(c, z, sh * u);
        float z0 = __shfl(zn, 0, 64);
        float v = acoshf(fmaxf(z0, 1.0f + 1e-7f));
        sp = (v >= 1.0f);
    };

    float z1; bool sp0;
    step(zo, z1, sp0);
    float r0 = sp0 ? zo : z1;

    float z = zo;
    bool at0 = true;
    for (int t = 0; t < T_STEPS; ++t) {
        float zn; bool sp;
        if (at0) { sp = sp0; zn = r0; }
        else {
            step(z, zn, sp);
            if (sp) zn = zo;
        }
        z_seq[(long)t * n * OUT_DIM_C + (long)node * OUT_DIM_C + lane] = zn;
        if (lane == 0) o_seq[(long)t * n + node] = sp ? 1.0f : 0.0f;
        z = zn;
        at0 = sp;
    }
}

extern "C" void kernel_launch(void* const* d_in, const int* in_sizes, int n_in,
                              void* d_out, int out_size, void* d_ws, size_t ws_size,
                              hipStream_t stream) {
    const float* x  = (const float*)d_in[0];
    const int*   ei = (const int*)d_in[1];
    const float* W  = (const float*)d_in[2];
    const float* b  = (const float*)d_in[3];
    const int N = in_sizes[0] / IN_DIM_C;   // 100000
    const int E = in_sizes[1] / 2;          // 1600000
    const int KC = (N + 255) >> 8;          // 391 coarse buckets

    float* out   = (float*)d_out;
    float* o_seq = out;                              // [T, N]
    float* z_seq = out + (long)T_STEPS * N;          // [T, N, 64]

    const int* srcp = ei;
    const int* dstp = ei + E;

    const long n_h = (long)N * OUT_DIM_C;
    const long n_meta = 2L * KC_MAX + (N + 1) + N;
    const size_t need = (size_t)(n_h + 2L * E + n_meta) * 4;

    float *h; int *part, *part2, *chist, *gcursor, *offsets; float *dinv;
    bool fused = (ws_size >= need);
    if (fused) {
        h       = (float*)d_ws;
        part    = (int*)(h + n_h);
        part2   = part + E;
        chist   = part2 + E;
    } else {
        h       = z_seq + 1L * n_h;
        part    = (int*)(z_seq + 2L * n_h);
        part2   = (int*)(z_seq + 3L * n_h);
        chist   = (int*)(z_seq + 4L * n_h);
    }
    gcursor = chist + KC_MAX;
    offsets = gcursor + KC_MAX;
    dinv    = (float*)(offsets + N + 1);

    hipMemsetAsync(chist, 0, (size_t)KC_MAX * sizeof(int), stream);
    k_hist<<<(E + 1023) / 1024, 256, 0, stream>>>(dstp, chist, E);
    k_scanK<<<1, 64, 0, stream>>>(chist, gcursor, offsets, KC, N, E);

    int n_groups = (N + 15) / 16;
    k_gemm<<<1024, 256, 0, stream>>>(x, W, h, N, n_groups);

    k_part<<<(E + PTILE - 1) / PTILE, 512, 0, stream>>>(srcp, dstp, gcursor, part, E, KC);
    k_sort<<<KC, 1024, 0, stream>>>(part, gcursor, part2, offsets, dinv, N);

    if (fused) {
        k_pullspike<<<(N * 64 + 255) / 256, 256, 0, stream>>>(offsets, part2, dinv, h, b,
                                                              o_seq, z_seq, N);
    } else {
        float* agg = z_seq;   // slab 0
        k_pull<<<(N * 64 + 255) / 256, 256, 0, stream>>>(offsets, part2, dinv, h, b, agg, N);
        k_spike<<<(N * 64 + 255) / 256, 256, 0, stream>>>(agg, o_seq, z_seq, N);
    }
}